// Round 8
// baseline (668.198 us; speedup 1.0000x reference)
//
#include <hip/hip_runtime.h>

// InteractionBlock (MACE-style) on MI355X — round 8.
// R7 post-mortem: gather3 163us = un-overlapped per-edge load chains
// (readfirstlane forces vmcnt drains; 8.3us/wave serial x 20000/1024 SIMDs
// = 163us exactly). Fix: k_gather4 = one block per node -> CSR offsets are
// provably scalar (s_load pipe), 4 waves split the node's edges, LDS combine.
// Also k_front merges prep+prepB+hist+node_up into one launch.
// k_mlp3 (MFMA, hi/lo bf16, fp32-grade) verbatim from R7 — validated.

typedef unsigned short u16;
typedef unsigned int u32;
typedef __attribute__((ext_vector_type(8))) short bf16x8;
typedef __attribute__((ext_vector_type(4))) float f32x4;

#define CW_UP0 0
#define CW_UP1 4096
#define CW_M1  8192
#define CW_M2  8704
#define CW_M3  12800
#define CW_M4  16896
#define CW_L0  37376
#define CW_L1  45568
#define CW_P0  57856
#define CW_P1  61952
#define CW_S01 66048
#define CW_S02 66688
#define CW_S03 67968
#define CW_S11 69248
#define CW_S12 69888
#define CW_S13 70528
#define CW_TOTAL 71808

#define C_SILU     1.6765224f
#define INV_SQRT3  0.57735027f
#define INV_SQRT2  0.70710678f
#define SC_L1      0.35355339f
#define SC_L234    0.125f

#define HSTRIDE 68
#define NFRAG   60

__device__ __forceinline__ float b2f(u16 u) {
  union { u32 i; float f; } x; x.i = ((u32)u) << 16; return x.f;
}
__device__ __forceinline__ u16 f2b(float f) {
  union { float f; u32 i; } x; x.f = f;
  u32 i = x.i;
  u32 r = (i + 0x7fffu + ((i >> 16) & 1u)) >> 16;
  return (u16)r;
}
__device__ __forceinline__ u32 pack_hl(float y) {
  u16 h = f2b(y);
  float r = y - b2f(h);
  u16 lo = f2b(r);
  return ((u32)h << 16) | (u32)lo;
}
__device__ __forceinline__ float ldf(const void* p, size_t i, int f32) {
  return f32 ? ((const float*)p)[i] : b2f(((const u16*)p)[i]);
}
__device__ __forceinline__ float silu_n(float x) {
  return C_SILU * x / (1.0f + __expf(-x));
}
__device__ __forceinline__ bf16x8 as_bf16x8(uint4 v) {
  union { uint4 u; bf16x8 b; } x; x.u = v; return x.b;
}

// ---- dtype detector
__global__ void k_detect(const void* nf, int* flag) {
  __shared__ int cnt;
  if (threadIdx.x == 0) cnt = 0;
  __syncthreads();
  const u16* p = (const u16*)nf;
  int wild = 0;
  for (int i = threadIdx.x; i < 4096; i += 256) {
    float ax = fabsf(b2f(p[i]));
    if (!(ax <= 1e10f) || (ax != 0.f && ax < 1e-10f)) wild++;
  }
  atomicAdd(&cnt, wild);
  __syncthreads();
  if (threadIdx.x == 0) *flag = (cnt > 100) ? 1 : 0;
}

struct WPtrs { const void* p[16]; };

// ---- front mega-kernel: [0,281) prep | [281,401) prepB | [401,nb0) hist |
// [nb0, nb0+ (nN+3)/4 ) node_up.  All branches depend only on detect+memset.
__global__ __launch_bounds__(256) void k_front(
    WPtrs wp, float* __restrict__ cw, u16* __restrict__ bwH,
    u16* __restrict__ bwL, const int* __restrict__ je, int* __restrict__ deg,
    const void* __restrict__ nf, float* __restrict__ sup,
    float* __restrict__ vup, int nN, int nE, int nb0,
    const int* __restrict__ flagp) {
  __shared__ float row[4][256];
  const int f32 = *flagp;
  int bid = blockIdx.x, tid = threadIdx.x;

  if (bid < 281) {                      // ---- prep: cw table
    const int   sizes[16]  = {4096,4096,512,4096,4096,20480,8192,12288,4096,
                              4096,640,1280,1280,640,640,1280};
    const float scales[16] = {0.125f,0.125f,0.35355339f,0.125f,0.125f,0.125f,
                              0.08838835f,0.07216878f,0.125f,0.125f,
                              1.f,1.f,1.f,1.f,1.f,1.f};
    int gid = bid * 256 + tid;
    if (gid >= CW_TOTAL) return;
    int off = gid, seg = 0;
    while (off >= sizes[seg]) { off -= sizes[seg]; seg++; }
    cw[gid] = ldf(wp.p[seg], off, f32) * scales[seg];
  } else if (bid < 401) {               // ---- prepB: MFMA B-fragments hi/lo
    int gid = (bid - 281) * 256 + tid;  // < 30720 exactly
    int f = gid >> 9, idx = gid & 511;
    int l = idx >> 3, j = idx & 7;
    int q = l >> 4, col16 = l & 15;
    float v = 0.f;
    if (f < 4) {
      int k = q * 8 + j, n = f * 16 + col16;
      if (k < 8) v = ldf(wp.p[2], (size_t)k * 64 + n, f32);
    } else if (f < 20) {
      const void* w = (f < 12) ? wp.p[3] : wp.p[4];
      int t = (f < 12) ? f - 4 : f - 12;
      int n = (t >> 1) * 16 + col16, ks = t & 1;
      int k = ks * 32 + q * 8 + j;
      v = ldf(w, (size_t)k * 64 + n, f32);
    } else {
      int t = f - 20;
      int n = (t >> 1) * 16 + col16, ks = t & 1;
      int k = ks * 32 + q * 8 + j;
      v = ldf(wp.p[5], (size_t)k * 320 + n, f32);
    }
    u16 hi = f2b(v);
    u16 lo = f2b(v - b2f(hi));
    size_t o = (size_t)f * 512 + (size_t)l * 8 + j;
    bwH[o] = hi;
    bwL[o] = lo;
  } else if (bid < nb0) {               // ---- hist
    int e = (bid - 401) * 256 + tid;
    if (e < nE) atomicAdd(&deg[je[e]], 1);
  } else {                              // ---- node_up (raw weights)
    int w = tid >> 6, l = tid & 63;
    int n = (bid - nb0) * 4 + w;
    bool valid = n < nN;
    int nn = valid ? n : 0;
#pragma unroll
    for (int t = 0; t < 4; t++)
      row[w][t * 64 + l] = ldf(nf, (size_t)nn * 256 + t * 64 + l, f32);
    __syncthreads();
    float sacc = 0.f, v0 = 0.f, v1 = 0.f, v2 = 0.f;
#pragma unroll 8
    for (int c = 0; c < 64; c++) {
      float w0 = ldf(wp.p[0], (size_t)c * 64 + l, f32);
      float w1 = ldf(wp.p[1], (size_t)c * 64 + l, f32);
      sacc += row[w][c] * w0;
      v0 += row[w][64 + c * 3 + 0] * w1;
      v1 += row[w][64 + c * 3 + 1] * w1;
      v2 += row[w][64 + c * 3 + 2] * w1;
    }
    if (valid) {
      sup[(size_t)n * 64 + l] = sacc * 0.125f;
      vup[((size_t)n * 3 + 0) * 64 + l] = v0 * 0.125f;
      vup[((size_t)n * 3 + 1) * 64 + l] = v1 * 0.125f;
      vup[((size_t)n * 3 + 2) * 64 + l] = v2 * 0.125f;
    }
  }
}

// ---- CSR scan + scatter
__global__ __launch_bounds__(256) void k_scan(const int* __restrict__ deg,
                                              int* __restrict__ offs,
                                              int* __restrict__ cursor, int nN) {
  __shared__ int part[256];
  int t = threadIdx.x;
  int per = (nN + 255) / 256;
  int lo = t * per, hi = (t + 1) * per; if (hi > nN) hi = nN;
  int s = 0;
  for (int i = lo; i < hi; i++) s += deg[i];
  part[t] = s;
  __syncthreads();
  if (t == 0) {
    int run = 0;
    for (int i = 0; i < 256; i++) { int v = part[i]; part[i] = run; run += v; }
    offs[nN] = run;
  }
  __syncthreads();
  int run = part[t];
  for (int i = lo; i < hi; i++) {
    offs[i] = run; cursor[i] = run; run += deg[i];
  }
}

__global__ __launch_bounds__(256) void k_scatter(const int* __restrict__ je,
                                                 int* __restrict__ cursor,
                                                 int* __restrict__ eidx, int nE) {
  int e = blockIdx.x * 256 + threadIdx.x;
  if (e < nE) {
    int pos = atomicAdd(&cursor[je[e]], 1);
    eidx[pos] = e;
  }
}

// ---- MFMA edge MLP (verbatim R7): one wave = 64 edge-slots, hi/lo bf16.
__global__ __launch_bounds__(192) void k_mlp3(
    const void* __restrict__ ef, const int* __restrict__ eidx,
    const int* __restrict__ offs, const u16* __restrict__ bwH,
    const u16* __restrict__ bwL, u16* __restrict__ tpw,
    int gn0, int gn1, int capEff, const int* __restrict__ flagp) {
  __shared__ u32 H[3][64 * HSTRIDE];
  const int f32 = *flagp;
  int tid = threadIdx.x;
  int w = tid >> 6, l = tid & 63;
  int m = l & 15, q = l >> 4;
  int base = offs[gn0];
  int cnt = offs[gn1] - base;
  int lim = cnt < capEff ? cnt : capEff;
  int tb = (blockIdx.x * 3 + w) * 64;
  if (tb >= lim) return;
  u32* Hw = H[w];

  bf16x8 zero8 = {0,0,0,0,0,0,0,0};
  bf16x8 A1h[4], A1l[4];
#pragma unroll
  for (int t = 0; t < 4; t++) { A1h[t] = zero8; A1l[t] = zero8; }
  if (q == 0) {
#pragma unroll
    for (int t = 0; t < 4; t++) {
      int s = tb + t * 16 + m; if (s > lim - 1) s = lim - 1;
      int eid = eidx[base + s];
      if (f32) {
        const float4* p = (const float4*)ef;
        float4 q0 = p[(size_t)eid * 2], q1 = p[(size_t)eid * 2 + 1];
        float v[8] = {q0.x, q0.y, q0.z, q0.w, q1.x, q1.y, q1.z, q1.w};
        bf16x8 hi, lo;
#pragma unroll
        for (int j = 0; j < 8; j++) {
          u16 h = f2b(v[j]);
          hi[j] = (short)h;
          lo[j] = (short)f2b(v[j] - b2f(h));
        }
        A1h[t] = hi; A1l[t] = lo;
      } else {
        uint4 r = ((const uint4*)ef)[eid];
        A1h[t] = as_bf16x8(r);
      }
    }
  }
#pragma unroll
  for (int n = 0; n < 4; n++) {
    bf16x8 Bh = *(const bf16x8*)(bwH + (size_t)n * 512 + (size_t)l * 8);
    bf16x8 Bl = *(const bf16x8*)(bwL + (size_t)n * 512 + (size_t)l * 8);
#pragma unroll
    for (int t = 0; t < 4; t++) {
      f32x4 c = (f32x4){0.f, 0.f, 0.f, 0.f};
      c = __builtin_amdgcn_mfma_f32_16x16x32_bf16(A1h[t], Bh, c, 0, 0, 0);
      c = __builtin_amdgcn_mfma_f32_16x16x32_bf16(A1l[t], Bh, c, 0, 0, 0);
      c = __builtin_amdgcn_mfma_f32_16x16x32_bf16(A1h[t], Bl, c, 0, 0, 0);
#pragma unroll
      for (int r = 0; r < 4; r++) {
        float y = silu_n(c[r] * SC_L1);
        Hw[(t * 16 + q * 4 + r) * HSTRIDE + n * 16 + m] = pack_hl(y);
      }
    }
  }

#pragma unroll
  for (int layer = 0; layer < 2; layer++) {
    int fragBase = 4 + layer * 8;
    bf16x8 Ah[2][4], Al[2][4];
#pragma unroll
    for (int ks = 0; ks < 2; ks++)
#pragma unroll
      for (int t = 0; t < 4; t++) {
        const uint4* hp =
            (const uint4*)(Hw + (t * 16 + m) * HSTRIDE + ks * 32 + q * 8);
        uint4 v0 = hp[0], v1 = hp[1];
        u32 raw[8] = {v0.x, v0.y, v0.z, v0.w, v1.x, v1.y, v1.z, v1.w};
        bf16x8 hi, lo;
#pragma unroll
        for (int j = 0; j < 8; j++) {
          hi[j] = (short)(raw[j] >> 16);
          lo[j] = (short)(raw[j] & 0xffffu);
        }
        Ah[ks][t] = hi; Al[ks][t] = lo;
      }
#pragma unroll
    for (int n = 0; n < 4; n++) {
      bf16x8 B0h = *(const bf16x8*)(bwH + (size_t)(fragBase + n * 2 + 0) * 512 +
                                    (size_t)l * 8);
      bf16x8 B0l = *(const bf16x8*)(bwL + (size_t)(fragBase + n * 2 + 0) * 512 +
                                    (size_t)l * 8);
      bf16x8 B1h = *(const bf16x8*)(bwH + (size_t)(fragBase + n * 2 + 1) * 512 +
                                    (size_t)l * 8);
      bf16x8 B1l = *(const bf16x8*)(bwL + (size_t)(fragBase + n * 2 + 1) * 512 +
                                    (size_t)l * 8);
#pragma unroll
      for (int t = 0; t < 4; t++) {
        f32x4 c = (f32x4){0.f, 0.f, 0.f, 0.f};
        c = __builtin_amdgcn_mfma_f32_16x16x32_bf16(Ah[0][t], B0h, c, 0, 0, 0);
        c = __builtin_amdgcn_mfma_f32_16x16x32_bf16(Al[0][t], B0h, c, 0, 0, 0);
        c = __builtin_amdgcn_mfma_f32_16x16x32_bf16(Ah[0][t], B0l, c, 0, 0, 0);
        c = __builtin_amdgcn_mfma_f32_16x16x32_bf16(Ah[1][t], B1h, c, 0, 0, 0);
        c = __builtin_amdgcn_mfma_f32_16x16x32_bf16(Al[1][t], B1h, c, 0, 0, 0);
        c = __builtin_amdgcn_mfma_f32_16x16x32_bf16(Ah[1][t], B1l, c, 0, 0, 0);
#pragma unroll
        for (int r = 0; r < 4; r++) {
          float y = silu_n(c[r] * SC_L234);
          Hw[(t * 16 + q * 4 + r) * HSTRIDE + n * 16 + m] = pack_hl(y);
        }
      }
    }
  }

  {
    bf16x8 Ah[2][4], Al[2][4];
#pragma unroll
    for (int ks = 0; ks < 2; ks++)
#pragma unroll
      for (int t = 0; t < 4; t++) {
        const uint4* hp =
            (const uint4*)(Hw + (t * 16 + m) * HSTRIDE + ks * 32 + q * 8);
        uint4 v0 = hp[0], v1 = hp[1];
        u32 raw[8] = {v0.x, v0.y, v0.z, v0.w, v1.x, v1.y, v1.z, v1.w};
        bf16x8 hi, lo;
#pragma unroll
        for (int j = 0; j < 8; j++) {
          hi[j] = (short)(raw[j] >> 16);
          lo[j] = (short)(raw[j] & 0xffffu);
        }
        Ah[ks][t] = hi; Al[ks][t] = lo;
      }
    for (int n = 0; n < 20; n++) {
      bf16x8 B0h = *(const bf16x8*)(bwH + (size_t)(20 + n * 2 + 0) * 512 +
                                    (size_t)l * 8);
      bf16x8 B0l = *(const bf16x8*)(bwL + (size_t)(20 + n * 2 + 0) * 512 +
                                    (size_t)l * 8);
      bf16x8 B1h = *(const bf16x8*)(bwH + (size_t)(20 + n * 2 + 1) * 512 +
                                    (size_t)l * 8);
      bf16x8 B1l = *(const bf16x8*)(bwL + (size_t)(20 + n * 2 + 1) * 512 +
                                    (size_t)l * 8);
#pragma unroll
      for (int t = 0; t < 4; t++) {
        f32x4 c = (f32x4){0.f, 0.f, 0.f, 0.f};
        c = __builtin_amdgcn_mfma_f32_16x16x32_bf16(Ah[0][t], B0h, c, 0, 0, 0);
        c = __builtin_amdgcn_mfma_f32_16x16x32_bf16(Al[0][t], B0h, c, 0, 0, 0);
        c = __builtin_amdgcn_mfma_f32_16x16x32_bf16(Ah[0][t], B0l, c, 0, 0, 0);
        c = __builtin_amdgcn_mfma_f32_16x16x32_bf16(Ah[1][t], B1h, c, 0, 0, 0);
        c = __builtin_amdgcn_mfma_f32_16x16x32_bf16(Al[1][t], B1h, c, 0, 0, 0);
        c = __builtin_amdgcn_mfma_f32_16x16x32_bf16(Ah[1][t], B1l, c, 0, 0, 0);
#pragma unroll
        for (int r = 0; r < 4; r++) {
          int srow = tb + t * 16 + q * 4 + r;
          if (srow < lim)
            tpw[(size_t)srow * 320 + n * 16 + m] = f2b(c[r] * SC_L234);
        }
      }
    }
  }
}

// ---- gather v4: one block (4 waves) per node; scalar CSR loads; LDS combine
__global__ __launch_bounds__(256) void k_gather4(
    const void* __restrict__ ea, const int* __restrict__ ie,
    const int* __restrict__ offs, const int* __restrict__ eidx,
    const float* __restrict__ sup, const float* __restrict__ vup,
    const int* __restrict__ an, const float* __restrict__ cw,
    const u16* __restrict__ tpw, void* __restrict__ out,
    int gn0, int capEff, const int* __restrict__ flagp) {
  __shared__ float part[4][11][64];
  __shared__ float Bb[960];
  const int f32 = *flagp;
  int tid = threadIdx.x;
  int w = __builtin_amdgcn_readfirstlane(tid >> 6);
  int l = tid & 63;
  int n = gn0 + blockIdx.x;
  int gbase = offs[gn0];
  int start = offs[n];
  int deg = offs[n + 1] - start;
  int avail = capEff - (start - gbase);
  int dmax = deg < avail ? deg : avail;
  if (dmax < 0) dmax = 0;
  int dend = start + dmax;

  float as0 = 0.f, as1 = 0.f;
  float av[9];
#pragma unroll
  for (int m = 0; m < 9; m++) av[m] = 0.f;

  int s0 = start + w;
  int eeC = 0, iC = 0;
  if (s0 < dend) { eeC = eidx[s0]; iC = ie[eeC]; }
  for (int s = s0; s < dend; s += 4) {
    int sn = s + 4, eeN = 0, iN = 0;
    if (sn < dend) { eeN = eidx[sn]; iN = ie[eeN]; }   // prefetch next
    const u16* tp = tpw + (size_t)(s - gbase) * 320;
    float wa  = b2f(tp[l]);
    float wbv = b2f(tp[64 + l]);
    float wc  = b2f(tp[128 + l]);
    float wd  = b2f(tp[192 + l]);
    float we_ = b2f(tp[256 + l]);
    float eas, ev0, ev1, ev2;
    if (f32) {
      const float4 r = ((const float4*)ea)[eeC];
      eas = r.x; ev0 = r.y; ev1 = r.z; ev2 = r.w;
    } else {
      uint2 r = ((const uint2*)ea)[eeC];
      eas = b2f(r.x & 0xffff); ev0 = b2f(r.x >> 16);
      ev1 = b2f(r.y & 0xffff); ev2 = b2f(r.y >> 16);
    }
    float xs  = sup[(size_t)iC * 64 + l];
    float xv0 = vup[((size_t)iC * 3 + 0) * 64 + l];
    float xv1 = vup[((size_t)iC * 3 + 1) * 64 + l];
    float xv2 = vup[((size_t)iC * 3 + 2) * 64 + l];
    float dot = xv0 * ev0 + xv1 * ev1 + xv2 * ev2;
    as0 += wa * xs * eas;
    as1 += wbv * dot * INV_SQRT3;
    float wcxs = wc * xs;
    float wde  = wd * eas;
    float wef  = we_ * INV_SQRT2;
    av[0] += wcxs * ev0; av[1] += wcxs * ev1; av[2] += wcxs * ev2;
    av[3] += wde * xv0;  av[4] += wde * xv1;  av[5] += wde * xv2;
    av[6] += wef * (xv1 * ev2 - xv2 * ev1);
    av[7] += wef * (xv2 * ev0 - xv0 * ev2);
    av[8] += wef * (xv0 * ev1 - xv1 * ev0);
    eeC = eeN; iC = iN;
  }

  part[w][0][l] = as0;
  part[w][1][l] = as1;
#pragma unroll
  for (int m = 0; m < 9; m++) part[w][2 + m][l] = av[m];
  __syncthreads();

  for (int j = w; j < 11; j += 4) {
    float sj = part[0][j][l] + part[1][j][l] + part[2][j][l] + part[3][j][l];
    if (j == 0)      Bb[l] = sj;
    else if (j == 1) Bb[64 + l] = sj;
    else if (j < 5)  Bb[128 + l * 3 + (j - 2)] = sj;
    else if (j < 8)  Bb[320 + l * 3 + (j - 5)] = sj;
    else             Bb[512 + l * 3 + (j - 8)] = sj;
  }
  __syncthreads();

  // ---- node-out epilogue (all waves compute redundantly; wave 0 stores)
  float s2 = 0.f;
#pragma unroll 8
  for (int c = 0; c < 128; c++) s2 += Bb[c] * cw[CW_L0 + c * 64 + l];
  float v20 = 0.f, v21 = 0.f, v22 = 0.f;
#pragma unroll 8
  for (int c = 0; c < 192; c++) {
    float wk = cw[CW_L1 + c * 64 + l];
    v20 += Bb[128 + c * 3 + 0] * wk;
    v21 += Bb[128 + c * 3 + 1] * wk;
    v22 += Bb[128 + c * 3 + 2] * wk;
  }
  int a = an[n];
  float w01  = cw[CW_S01 + a * 64 + l];
  float w02a = cw[CW_S02 + a * 128 + l];
  float w02b = cw[CW_S02 + a * 128 + 64 + l];
  float w03a = cw[CW_S03 + a * 128 + l];
  float w03b = cw[CW_S03 + a * 128 + 64 + l];
  float w11  = cw[CW_S11 + a * 64 + l];
  float w12  = cw[CW_S12 + a * 64 + l];
  float w13a = cw[CW_S13 + a * 128 + l];
  float w13b = cw[CW_S13 + a * 128 + 64 + l];

  float vv = v20 * v20 + v21 * v21 + v22 * v22;
  float s2sq = s2 * s2;
  float vvs = vv * INV_SQRT3;
  float outs = w01 * s2 + w02a * s2sq + w02b * vvs + w03a * s2sq * s2 +
               w03b * s2 * vvs;
  float coef = w11 + w12 * s2 + w13a * s2sq + w13b * vvs;

  __syncthreads();
  Bb[704 + l] = outs;                 // all waves write identical values
  Bb[768 + l * 3 + 0] = coef * v20;
  Bb[768 + l * 3 + 1] = coef * v21;
  Bb[768 + l * 3 + 2] = coef * v22;
  __syncthreads();

  float so = 0.f, vo0 = 0.f, vo1 = 0.f, vo2 = 0.f;
#pragma unroll 8
  for (int c = 0; c < 64; c++) {
    float w0 = cw[CW_P0 + c * 64 + l];
    float w1 = cw[CW_P1 + c * 64 + l];
    so  += Bb[704 + c] * w0;
    vo0 += Bb[768 + c * 3 + 0] * w1;
    vo1 += Bb[768 + c * 3 + 1] * w1;
    vo2 += Bb[768 + c * 3 + 2] * w1;
  }
  if (w == 0) {
    size_t basep = (size_t)n * 256;
    if (f32) {
      float* o = (float*)out;
      o[basep + l] = so;
      o[basep + 64 + l * 3 + 0] = vo0;
      o[basep + 64 + l * 3 + 1] = vo1;
      o[basep + 64 + l * 3 + 2] = vo2;
    } else {
      u16* o = (u16*)out;
      o[basep + l] = f2b(so);
      o[basep + 64 + l * 3 + 0] = f2b(vo0);
      o[basep + 64 + l * 3 + 1] = f2b(vo1);
      o[basep + 64 + l * 3 + 2] = f2b(vo2);
    }
  }
}

extern "C" void kernel_launch(void* const* d_in, const int* in_sizes, int n_in,
                              void* d_out, int out_size, void* d_ws,
                              size_t ws_size, hipStream_t stream) {
  const void* nf = d_in[0];
  const void* ef = d_in[1];
  const void* ea = d_in[2];
  const int* ie = (const int*)d_in[3];
  const int* je = (const int*)d_in[4];
  const int* an = (const int*)d_in[5];
  int nN = in_sizes[0] / 256;   // 20000
  int nE = in_sizes[3];         // 320000

  size_t intCnt = (size_t)3 * nN + 1 + nE;
  intCnt = (intCnt + 3) & ~(size_t)3;
  int* deg    = (int*)d_ws;
  int* offs   = deg + nN;
  int* cursor = offs + nN + 1;
  int* eidx   = cursor + nN;
  float* cw   = (float*)d_ws + intCnt;
  float* sup  = cw + CW_TOTAL;
  float* vup  = sup + (size_t)nN * 64;
  int* flag   = (int*)(vup + (size_t)nN * 192);

  size_t bwByte = (intCnt + CW_TOTAL + (size_t)nN * 256 + 1) * 4;
  bwByte = (bwByte + 15) & ~(size_t)15;
  u16* bwH = (u16*)((char*)d_ws + bwByte);
  u16* bwL = bwH + (size_t)NFRAG * 512;
  size_t tpwByte = bwByte + (size_t)NFRAG * 512 * 2 * 2;
  tpwByte = (tpwByte + 15) & ~(size_t)15;
  u16* tpw = (u16*)((char*)d_ws + tpwByte);
  size_t capE = (ws_size > tpwByte) ? (ws_size - tpwByte) / 640 : 0;

  int G = 64;
  int nodesPer = (nN + 63) / 64;
  for (int g = 1; g <= 64; g++) {
    int npg = (nN + g - 1) / g;
    size_t worst = (size_t)npg * nE / nN + 6000;
    if (worst <= capE) { G = g; nodesPer = npg; break; }
  }
  int capEff = (int)((size_t)nodesPer * nE / nN + 6000);
  if ((size_t)capEff > capE) capEff = (int)capE;

  k_detect<<<1, 256, 0, stream>>>(nf, flag);
  hipMemsetAsync(deg, 0, (size_t)nN * sizeof(int), stream);

  WPtrs wp;
  const int widx[16] = {6, 7, 8, 9, 10, 11, 12, 13, 20, 21,
                        14, 15, 16, 17, 18, 19};
  for (int i = 0; i < 16; i++) wp.p[i] = d_in[widx[i]];

  int histNB = (nE + 255) / 256;
  int nb0 = 401 + histNB;
  int nupNB = (nN + 3) / 4;
  k_front<<<nb0 + nupNB, 256, 0, stream>>>(wp, cw, bwH, bwL, je, deg, nf,
                                           sup, vup, nN, nE, nb0, flag);
  k_scan<<<1, 256, 0, stream>>>(deg, offs, cursor, nN);
  k_scatter<<<(nE + 255) / 256, 256, 0, stream>>>(je, cursor, eidx, nE);

  for (int g = 0; g < G; g++) {
    int gn0 = g * nodesPer;
    if (gn0 >= nN) break;
    int gn1 = gn0 + nodesPer; if (gn1 > nN) gn1 = nN;
    int mlp3Blocks = (capEff + 191) / 192;
    k_mlp3<<<mlp3Blocks, 192, 0, stream>>>(ef, eidx, offs, bwH, bwL, tpw,
                                           gn0, gn1, capEff, flag);
    k_gather4<<<gn1 - gn0, 256, 0, stream>>>(ea, ie, offs, eidx, sup, vup,
                                             an, cw, tpw, d_out, gn0, capEff,
                                             flag);
  }
}

// Round 9
// 475.695 us; speedup vs baseline: 1.4047x; 1.4047x over previous
//
#include <hip/hip_runtime.h>

// InteractionBlock (MACE-style) on MI355X — round 9.
// R8 post-mortem: one-block-per-node QUADRUPLED the epilogue (4 waves
// redundant) -> 360us. Model: E(edge loop)~98us, P(epilogue)~65us per R7.
// Fix: k_scatter2 pre-gathers ie/ea/ef into slot order (edge-parallel,
// coalesced) -> k_gather5 (one wave/node, epilogue once) has NO VMEM in the
// per-edge dependency chain (indices/attrs preloaded per 64-chunk, __shfl
// broadcast). k_mlp4: bf16 activations (weights stay hi/lo exact) -> 2/3
// MFMA count, half LDS, direct b128->bf16x8 A-fragment reads.

typedef unsigned short u16;
typedef unsigned int u32;
typedef __attribute__((ext_vector_type(8))) short bf16x8;
typedef __attribute__((ext_vector_type(4))) float f32x4;

#define CW_UP0 0
#define CW_UP1 4096
#define CW_M1  8192
#define CW_M2  8704
#define CW_M3  12800
#define CW_M4  16896
#define CW_L0  37376
#define CW_L1  45568
#define CW_P0  57856
#define CW_P1  61952
#define CW_S01 66048
#define CW_S02 66688
#define CW_S03 67968
#define CW_S11 69248
#define CW_S12 69888
#define CW_S13 70528
#define CW_TOTAL 71808

#define C_SILU     1.6765224f
#define INV_SQRT3  0.57735027f
#define INV_SQRT2  0.70710678f
#define SC_L1      0.35355339f
#define SC_L234    0.125f

#define HS16 72             // u16 per h-row (64 + pad 8): rows 144B, 16B-aligned
#define NFRAG   60

__device__ __forceinline__ float b2f(u16 u) {
  union { u32 i; float f; } x; x.i = ((u32)u) << 16; return x.f;
}
__device__ __forceinline__ u16 f2b(float f) {
  union { float f; u32 i; } x; x.f = f;
  u32 i = x.i;
  u32 r = (i + 0x7fffu + ((i >> 16) & 1u)) >> 16;
  return (u16)r;
}
__device__ __forceinline__ float ldf(const void* p, size_t i, int f32) {
  return f32 ? ((const float*)p)[i] : b2f(((const u16*)p)[i]);
}
__device__ __forceinline__ float silu_n(float x) {
  return C_SILU * x / (1.0f + __expf(-x));
}

// ---- dtype detector
__global__ void k_detect(const void* nf, int* flag) {
  __shared__ int cnt;
  if (threadIdx.x == 0) cnt = 0;
  __syncthreads();
  const u16* p = (const u16*)nf;
  int wild = 0;
  for (int i = threadIdx.x; i < 4096; i += 256) {
    float ax = fabsf(b2f(p[i]));
    if (!(ax <= 1e10f) || (ax != 0.f && ax < 1e-10f)) wild++;
  }
  atomicAdd(&cnt, wild);
  __syncthreads();
  if (threadIdx.x == 0) *flag = (cnt > 100) ? 1 : 0;
}

struct WPtrs { const void* p[16]; };

// ---- front mega-kernel: prep | prepB | hist | node_up
__global__ __launch_bounds__(256) void k_front(
    WPtrs wp, float* __restrict__ cw, u16* __restrict__ bwH,
    u16* __restrict__ bwL, const int* __restrict__ je, int* __restrict__ deg,
    const void* __restrict__ nf, float* __restrict__ sup,
    float* __restrict__ vup, int nN, int nE, int nb0,
    const int* __restrict__ flagp) {
  __shared__ float row[4][256];
  const int f32 = *flagp;
  int bid = blockIdx.x, tid = threadIdx.x;

  if (bid < 281) {                      // ---- prep: cw table
    const int   sizes[16]  = {4096,4096,512,4096,4096,20480,8192,12288,4096,
                              4096,640,1280,1280,640,640,1280};
    const float scales[16] = {0.125f,0.125f,0.35355339f,0.125f,0.125f,0.125f,
                              0.08838835f,0.07216878f,0.125f,0.125f,
                              1.f,1.f,1.f,1.f,1.f,1.f};
    int gid = bid * 256 + tid;
    if (gid >= CW_TOTAL) return;
    int off = gid, seg = 0;
    while (off >= sizes[seg]) { off -= sizes[seg]; seg++; }
    cw[gid] = ldf(wp.p[seg], off, f32) * scales[seg];
  } else if (bid < 401) {               // ---- prepB: MFMA B-fragments hi/lo
    int gid = (bid - 281) * 256 + tid;  // < 30720 exactly
    int f = gid >> 9, idx = gid & 511;
    int l = idx >> 3, j = idx & 7;
    int q = l >> 4, col16 = l & 15;
    float v = 0.f;
    if (f < 4) {
      int k = q * 8 + j, n = f * 16 + col16;
      if (k < 8) v = ldf(wp.p[2], (size_t)k * 64 + n, f32);
    } else if (f < 20) {
      const void* w = (f < 12) ? wp.p[3] : wp.p[4];
      int t = (f < 12) ? f - 4 : f - 12;
      int n = (t >> 1) * 16 + col16, ks = t & 1;
      int k = ks * 32 + q * 8 + j;
      v = ldf(w, (size_t)k * 64 + n, f32);
    } else {
      int t = f - 20;
      int n = (t >> 1) * 16 + col16, ks = t & 1;
      int k = ks * 32 + q * 8 + j;
      v = ldf(wp.p[5], (size_t)k * 320 + n, f32);
    }
    u16 hi = f2b(v);
    u16 lo = f2b(v - b2f(hi));
    size_t o = (size_t)f * 512 + (size_t)l * 8 + j;
    bwH[o] = hi;
    bwL[o] = lo;
  } else if (bid < nb0) {               // ---- hist
    int e = (bid - 401) * 256 + tid;
    if (e < nE) atomicAdd(&deg[je[e]], 1);
  } else {                              // ---- node_up (raw weights)
    int w = tid >> 6, l = tid & 63;
    int n = (bid - nb0) * 4 + w;
    bool valid = n < nN;
    int nn = valid ? n : 0;
#pragma unroll
    for (int t = 0; t < 4; t++)
      row[w][t * 64 + l] = ldf(nf, (size_t)nn * 256 + t * 64 + l, f32);
    __syncthreads();
    float sacc = 0.f, v0 = 0.f, v1 = 0.f, v2 = 0.f;
#pragma unroll 8
    for (int c = 0; c < 64; c++) {
      float w0 = ldf(wp.p[0], (size_t)c * 64 + l, f32);
      float w1 = ldf(wp.p[1], (size_t)c * 64 + l, f32);
      sacc += row[w][c] * w0;
      v0 += row[w][64 + c * 3 + 0] * w1;
      v1 += row[w][64 + c * 3 + 1] * w1;
      v2 += row[w][64 + c * 3 + 2] * w1;
    }
    if (valid) {
      sup[(size_t)n * 64 + l] = sacc * 0.125f;
      vup[((size_t)n * 3 + 0) * 64 + l] = v0 * 0.125f;
      vup[((size_t)n * 3 + 1) * 64 + l] = v1 * 0.125f;
      vup[((size_t)n * 3 + 2) * 64 + l] = v2 * 0.125f;
    }
  }
}

// ---- CSR scan
__global__ __launch_bounds__(256) void k_scan(const int* __restrict__ deg,
                                              int* __restrict__ offs,
                                              int* __restrict__ cursor, int nN) {
  __shared__ int part[256];
  int t = threadIdx.x;
  int per = (nN + 255) / 256;
  int lo = t * per, hi = (t + 1) * per; if (hi > nN) hi = nN;
  int s = 0;
  for (int i = lo; i < hi; i++) s += deg[i];
  part[t] = s;
  __syncthreads();
  if (t == 0) {
    int run = 0;
    for (int i = 0; i < 256; i++) { int v = part[i]; part[i] = run; run += v; }
    offs[nN] = run;
  }
  __syncthreads();
  int run = part[t];
  for (int i = lo; i < hi; i++) {
    offs[i] = run; cursor[i] = run; run += deg[i];
  }
}

// ---- scatter2: CSR slot fill + pre-gather of ie/ea/ef into slot order (fp32)
__global__ __launch_bounds__(256) void k_scatter2(
    const int* __restrict__ je, const int* __restrict__ ie,
    const void* __restrict__ ea, const void* __restrict__ ef,
    int* __restrict__ cursor, int* __restrict__ iSlot,
    float4* __restrict__ eaSlot, float4* __restrict__ efSlot, int nE,
    const int* __restrict__ flagp) {
  const int f32 = *flagp;
  int e = blockIdx.x * 256 + threadIdx.x;
  if (e >= nE) return;
  int pos = atomicAdd(&cursor[je[e]], 1);
  iSlot[pos] = ie[e];
  float4 av;
  float4 f0, f1;
  if (f32) {
    av = ((const float4*)ea)[e];
    f0 = ((const float4*)ef)[(size_t)e * 2];
    f1 = ((const float4*)ef)[(size_t)e * 2 + 1];
  } else {
    uint2 r = ((const uint2*)ea)[e];
    av = make_float4(b2f(r.x & 0xffff), b2f(r.x >> 16),
                     b2f(r.y & 0xffff), b2f(r.y >> 16));
    uint4 u = ((const uint4*)ef)[e];
    f0 = make_float4(b2f(u.x & 0xffff), b2f(u.x >> 16),
                     b2f(u.y & 0xffff), b2f(u.y >> 16));
    f1 = make_float4(b2f(u.z & 0xffff), b2f(u.z >> 16),
                     b2f(u.w & 0xffff), b2f(u.w >> 16));
  }
  eaSlot[pos] = av;
  efSlot[(size_t)pos * 2] = f0;
  efSlot[(size_t)pos * 2 + 1] = f1;
}

// ---- MFMA edge MLP v4: one wave = 64 slots; bf16 activations in LDS (u16);
// weights hi/lo exact; L1 inputs hi/lo from fp32 efSlot.
__global__ __launch_bounds__(192) void k_mlp4(
    const float4* __restrict__ efSlot, const int* __restrict__ offs,
    const u16* __restrict__ bwH, const u16* __restrict__ bwL,
    u16* __restrict__ tpw, int gn0, int gn1, int capEff) {
  __shared__ u16 H[3][64 * HS16];
  int tid = threadIdx.x;
  int w = tid >> 6, l = tid & 63;
  int m = l & 15, q = l >> 4;
  int base = offs[gn0];
  int cnt = offs[gn1] - base;
  int lim = cnt < capEff ? cnt : capEff;
  int tb = (blockIdx.x * 3 + w) * 64;
  if (tb >= lim) return;
  u16* Hw = H[w];

  bf16x8 zero8 = {0,0,0,0,0,0,0,0};
  bf16x8 A1h[4], A1l[4];
#pragma unroll
  for (int t = 0; t < 4; t++) { A1h[t] = zero8; A1l[t] = zero8; }
  if (q == 0) {
#pragma unroll
    for (int t = 0; t < 4; t++) {
      int s = tb + t * 16 + m; if (s > lim - 1) s = lim - 1;
      float4 q0 = efSlot[(size_t)s * 2], q1 = efSlot[(size_t)s * 2 + 1];
      float v[8] = {q0.x, q0.y, q0.z, q0.w, q1.x, q1.y, q1.z, q1.w};
      bf16x8 hi, lo;
#pragma unroll
      for (int j = 0; j < 8; j++) {
        u16 h = f2b(v[j]);
        hi[j] = (short)h;
        lo[j] = (short)f2b(v[j] - b2f(h));
      }
      A1h[t] = hi; A1l[t] = lo;
    }
  }
  // L1: 3 MFMAs per (n,t)
#pragma unroll
  for (int n = 0; n < 4; n++) {
    bf16x8 Bh = *(const bf16x8*)(bwH + (size_t)n * 512 + (size_t)l * 8);
    bf16x8 Bl = *(const bf16x8*)(bwL + (size_t)n * 512 + (size_t)l * 8);
#pragma unroll
    for (int t = 0; t < 4; t++) {
      f32x4 c = (f32x4){0.f, 0.f, 0.f, 0.f};
      c = __builtin_amdgcn_mfma_f32_16x16x32_bf16(A1h[t], Bh, c, 0, 0, 0);
      c = __builtin_amdgcn_mfma_f32_16x16x32_bf16(A1l[t], Bh, c, 0, 0, 0);
      c = __builtin_amdgcn_mfma_f32_16x16x32_bf16(A1h[t], Bl, c, 0, 0, 0);
#pragma unroll
      for (int r = 0; r < 4; r++)
        Hw[(t * 16 + q * 4 + r) * HS16 + n * 16 + m] =
            f2b(silu_n(c[r] * SC_L1));
    }
  }

  // L2, L3: 4 MFMAs per (n,t): Ah*B{0,1}{h,l}
#pragma unroll
  for (int layer = 0; layer < 2; layer++) {
    int fragBase = 4 + layer * 8;
    bf16x8 Ah[2][4];
#pragma unroll
    for (int ks = 0; ks < 2; ks++)
#pragma unroll
      for (int t = 0; t < 4; t++)
        Ah[ks][t] = *(const bf16x8*)(Hw + (t * 16 + m) * HS16 + ks * 32 + q * 8);
#pragma unroll
    for (int n = 0; n < 4; n++) {
      bf16x8 B0h = *(const bf16x8*)(bwH + (size_t)(fragBase + n * 2 + 0) * 512 +
                                    (size_t)l * 8);
      bf16x8 B0l = *(const bf16x8*)(bwL + (size_t)(fragBase + n * 2 + 0) * 512 +
                                    (size_t)l * 8);
      bf16x8 B1h = *(const bf16x8*)(bwH + (size_t)(fragBase + n * 2 + 1) * 512 +
                                    (size_t)l * 8);
      bf16x8 B1l = *(const bf16x8*)(bwL + (size_t)(fragBase + n * 2 + 1) * 512 +
                                    (size_t)l * 8);
#pragma unroll
      for (int t = 0; t < 4; t++) {
        f32x4 c = (f32x4){0.f, 0.f, 0.f, 0.f};
        c = __builtin_amdgcn_mfma_f32_16x16x32_bf16(Ah[0][t], B0h, c, 0, 0, 0);
        c = __builtin_amdgcn_mfma_f32_16x16x32_bf16(Ah[0][t], B0l, c, 0, 0, 0);
        c = __builtin_amdgcn_mfma_f32_16x16x32_bf16(Ah[1][t], B1h, c, 0, 0, 0);
        c = __builtin_amdgcn_mfma_f32_16x16x32_bf16(Ah[1][t], B1l, c, 0, 0, 0);
#pragma unroll
        for (int r = 0; r < 4; r++)
          Hw[(t * 16 + q * 4 + r) * HS16 + n * 16 + m] =
              f2b(silu_n(c[r] * SC_L234));
      }
    }
  }

  // L4: 64 -> 320; store bf16 tpw[slot][320]
  {
    bf16x8 Ah[2][4];
#pragma unroll
    for (int ks = 0; ks < 2; ks++)
#pragma unroll
      for (int t = 0; t < 4; t++)
        Ah[ks][t] = *(const bf16x8*)(Hw + (t * 16 + m) * HS16 + ks * 32 + q * 8);
    for (int n = 0; n < 20; n++) {
      bf16x8 B0h = *(const bf16x8*)(bwH + (size_t)(20 + n * 2 + 0) * 512 +
                                    (size_t)l * 8);
      bf16x8 B0l = *(const bf16x8*)(bwL + (size_t)(20 + n * 2 + 0) * 512 +
                                    (size_t)l * 8);
      bf16x8 B1h = *(const bf16x8*)(bwH + (size_t)(20 + n * 2 + 1) * 512 +
                                    (size_t)l * 8);
      bf16x8 B1l = *(const bf16x8*)(bwL + (size_t)(20 + n * 2 + 1) * 512 +
                                    (size_t)l * 8);
#pragma unroll
      for (int t = 0; t < 4; t++) {
        f32x4 c = (f32x4){0.f, 0.f, 0.f, 0.f};
        c = __builtin_amdgcn_mfma_f32_16x16x32_bf16(Ah[0][t], B0h, c, 0, 0, 0);
        c = __builtin_amdgcn_mfma_f32_16x16x32_bf16(Ah[0][t], B0l, c, 0, 0, 0);
        c = __builtin_amdgcn_mfma_f32_16x16x32_bf16(Ah[1][t], B1h, c, 0, 0, 0);
        c = __builtin_amdgcn_mfma_f32_16x16x32_bf16(Ah[1][t], B1l, c, 0, 0, 0);
#pragma unroll
        for (int r = 0; r < 4; r++) {
          int srow = tb + t * 16 + q * 4 + r;
          if (srow < lim)
            tpw[(size_t)srow * 320 + n * 16 + m] = f2b(c[r] * SC_L234);
        }
      }
    }
  }
}

// ---- gather v5: one wave per node; slot-ordered metadata in registers,
// __shfl broadcast -> no VMEM in per-edge dependency chain.
__global__ __launch_bounds__(256) void k_gather5(
    const int* __restrict__ iSlot, const float4* __restrict__ eaSlot,
    const int* __restrict__ offs, const float* __restrict__ sup,
    const float* __restrict__ vup, const int* __restrict__ an,
    const float* __restrict__ cw, const u16* __restrict__ tpw,
    void* __restrict__ out, int gn0, int gn1, int capEff,
    const int* __restrict__ flagp) {
  __shared__ float B[4][960];
  const int f32 = *flagp;
  int w = threadIdx.x >> 6, l = threadIdx.x & 63;
  int n = gn0 + blockIdx.x * 4 + w;
  bool valid = n < gn1;
  int nn = valid ? n : gn0;
  int gbase = offs[gn0];
  int start = offs[nn];
  int deg = offs[nn + 1] - start;
  int avail = capEff - (start - gbase);
  int dmax = deg < avail ? deg : avail;
  if (dmax < 0) dmax = 0;

  float as0 = 0.f, as1 = 0.f;
  float av[9];
#pragma unroll
  for (int m = 0; m < 9; m++) av[m] = 0.f;

  for (int c0 = 0; c0 < dmax; c0 += 64) {
    int rem = dmax - c0;
    int cend = rem < 64 ? rem : 64;
    int iA = 0;
    float4 eaA = make_float4(0.f, 0.f, 0.f, 0.f);
    if (l < cend) {
      iA = iSlot[start + c0 + l];
      eaA = eaSlot[start + c0 + l];
    }
    for (int qq = 0; qq < cend; qq++) {
      int i = __shfl(iA, qq);
      float eas = __shfl(eaA.x, qq);
      float ev0 = __shfl(eaA.y, qq);
      float ev1 = __shfl(eaA.z, qq);
      float ev2 = __shfl(eaA.w, qq);
      const u16* tp = tpw + (size_t)(start - gbase + c0 + qq) * 320;
      float wa  = b2f(tp[l]);
      float wbv = b2f(tp[64 + l]);
      float wc  = b2f(tp[128 + l]);
      float wd  = b2f(tp[192 + l]);
      float we_ = b2f(tp[256 + l]);
      float xs  = sup[(size_t)i * 64 + l];
      float xv0 = vup[((size_t)i * 3 + 0) * 64 + l];
      float xv1 = vup[((size_t)i * 3 + 1) * 64 + l];
      float xv2 = vup[((size_t)i * 3 + 2) * 64 + l];
      float dot = xv0 * ev0 + xv1 * ev1 + xv2 * ev2;
      as0 += wa * xs * eas;
      as1 += wbv * dot * INV_SQRT3;
      float wcxs = wc * xs;
      float wde  = wd * eas;
      float wef  = we_ * INV_SQRT2;
      av[0] += wcxs * ev0; av[1] += wcxs * ev1; av[2] += wcxs * ev2;
      av[3] += wde * xv0;  av[4] += wde * xv1;  av[5] += wde * xv2;
      av[6] += wef * (xv1 * ev2 - xv2 * ev1);
      av[7] += wef * (xv2 * ev0 - xv0 * ev2);
      av[8] += wef * (xv0 * ev1 - xv1 * ev0);
    }
  }

  float* Bb = B[w];
  Bb[l] = as0;
  Bb[64 + l] = as1;
#pragma unroll
  for (int m = 0; m < 3; m++) {
    Bb[128 + l * 3 + m] = av[m];
    Bb[320 + l * 3 + m] = av[3 + m];
    Bb[512 + l * 3 + m] = av[6 + m];
  }
  __syncthreads();

  float s2 = 0.f;
#pragma unroll 8
  for (int c = 0; c < 128; c++) s2 += Bb[c] * cw[CW_L0 + c * 64 + l];
  float v20 = 0.f, v21 = 0.f, v22 = 0.f;
#pragma unroll 8
  for (int c = 0; c < 192; c++) {
    float wk = cw[CW_L1 + c * 64 + l];
    v20 += Bb[128 + c * 3 + 0] * wk;
    v21 += Bb[128 + c * 3 + 1] * wk;
    v22 += Bb[128 + c * 3 + 2] * wk;
  }
  int a = an[nn];
  float w01  = cw[CW_S01 + a * 64 + l];
  float w02a = cw[CW_S02 + a * 128 + l];
  float w02b = cw[CW_S02 + a * 128 + 64 + l];
  float w03a = cw[CW_S03 + a * 128 + l];
  float w03b = cw[CW_S03 + a * 128 + 64 + l];
  float w11  = cw[CW_S11 + a * 64 + l];
  float w12  = cw[CW_S12 + a * 64 + l];
  float w13a = cw[CW_S13 + a * 128 + l];
  float w13b = cw[CW_S13 + a * 128 + 64 + l];

  float vv = v20 * v20 + v21 * v21 + v22 * v22;
  float s2sq = s2 * s2;
  float vvs = vv * INV_SQRT3;
  float outs = w01 * s2 + w02a * s2sq + w02b * vvs + w03a * s2sq * s2 +
               w03b * s2 * vvs;
  float coef = w11 + w12 * s2 + w13a * s2sq + w13b * vvs;

  __syncthreads();
  Bb[704 + l] = outs;
  Bb[768 + l * 3 + 0] = coef * v20;
  Bb[768 + l * 3 + 1] = coef * v21;
  Bb[768 + l * 3 + 2] = coef * v22;
  __syncthreads();

  float so = 0.f, vo0 = 0.f, vo1 = 0.f, vo2 = 0.f;
#pragma unroll 8
  for (int c = 0; c < 64; c++) {
    float w0 = cw[CW_P0 + c * 64 + l];
    float w1 = cw[CW_P1 + c * 64 + l];
    so  += Bb[704 + c] * w0;
    vo0 += Bb[768 + c * 3 + 0] * w1;
    vo1 += Bb[768 + c * 3 + 1] * w1;
    vo2 += Bb[768 + c * 3 + 2] * w1;
  }
  if (valid) {
    size_t basep = (size_t)n * 256;
    if (f32) {
      float* o = (float*)out;
      o[basep + l] = so;
      o[basep + 64 + l * 3 + 0] = vo0;
      o[basep + 64 + l * 3 + 1] = vo1;
      o[basep + 64 + l * 3 + 2] = vo2;
    } else {
      u16* o = (u16*)out;
      o[basep + l] = f2b(so);
      o[basep + 64 + l * 3 + 0] = f2b(vo0);
      o[basep + 64 + l * 3 + 1] = f2b(vo1);
      o[basep + 64 + l * 3 + 2] = f2b(vo2);
    }
  }
}

extern "C" void kernel_launch(void* const* d_in, const int* in_sizes, int n_in,
                              void* d_out, int out_size, void* d_ws,
                              size_t ws_size, hipStream_t stream) {
  const void* nf = d_in[0];
  const void* ef = d_in[1];
  const void* ea = d_in[2];
  const int* ie = (const int*)d_in[3];
  const int* je = (const int*)d_in[4];
  const int* an = (const int*)d_in[5];
  int nN = in_sizes[0] / 256;   // 20000
  int nE = in_sizes[3];         // 320000

  size_t intCnt = (size_t)3 * nN + 1 + nE;     // deg, offs, cursor, iSlot
  intCnt = (intCnt + 3) & ~(size_t)3;
  int* deg    = (int*)d_ws;
  int* offs   = deg + nN;
  int* cursor = offs + nN + 1;
  int* iSlot  = cursor + nN;
  float* cw   = (float*)d_ws + intCnt;
  float* sup  = cw + CW_TOTAL;
  float* vup  = sup + (size_t)nN * 64;
  int* flag   = (int*)(vup + (size_t)nN * 192);

  size_t eaByte = (intCnt + CW_TOTAL + (size_t)nN * 256 + 1) * 4;
  eaByte = (eaByte + 15) & ~(size_t)15;
  float4* eaSlot = (float4*)((char*)d_ws + eaByte);
  float4* efSlot = eaSlot + nE;                 // nE float4 x2 for ef
  size_t bwByte = eaByte + (size_t)nE * 16 + (size_t)nE * 32;
  u16* bwH = (u16*)((char*)d_ws + bwByte);
  u16* bwL = bwH + (size_t)NFRAG * 512;
  size_t tpwByte = bwByte + (size_t)NFRAG * 512 * 2 * 2;
  tpwByte = (tpwByte + 15) & ~(size_t)15;
  u16* tpw = (u16*)((char*)d_ws + tpwByte);
  size_t capE = (ws_size > tpwByte) ? (ws_size - tpwByte) / 640 : 0;

  int G = 64;
  int nodesPer = (nN + 63) / 64;
  for (int g = 1; g <= 64; g++) {
    int npg = (nN + g - 1) / g;
    size_t worst = (size_t)npg * nE / nN + 6000;
    if (worst <= capE) { G = g; nodesPer = npg; break; }
  }
  int capEff = (int)((size_t)nodesPer * nE / nN + 6000);
  if ((size_t)capEff > capE) capEff = (int)capE;

  k_detect<<<1, 256, 0, stream>>>(nf, flag);
  hipMemsetAsync(deg, 0, (size_t)nN * sizeof(int), stream);

  WPtrs wp;
  const int widx[16] = {6, 7, 8, 9, 10, 11, 12, 13, 20, 21,
                        14, 15, 16, 17, 18, 19};
  for (int i = 0; i < 16; i++) wp.p[i] = d_in[widx[i]];

  int histNB = (nE + 255) / 256;
  int nb0 = 401 + histNB;
  int nupNB = (nN + 3) / 4;
  k_front<<<nb0 + nupNB, 256, 0, stream>>>(wp, cw, bwH, bwL, je, deg, nf,
                                           sup, vup, nN, nE, nb0, flag);
  k_scan<<<1, 256, 0, stream>>>(deg, offs, cursor, nN);
  k_scatter2<<<(nE + 255) / 256, 256, 0, stream>>>(je, ie, ea, ef, cursor,
                                                   iSlot, eaSlot, efSlot, nE,
                                                   flag);

  for (int g = 0; g < G; g++) {
    int gn0 = g * nodesPer;
    if (gn0 >= nN) break;
    int gn1 = gn0 + nodesPer; if (gn1 > nN) gn1 = nN;
    int mlpBlocks = (capEff + 191) / 192;
    k_mlp4<<<mlpBlocks, 192, 0, stream>>>(efSlot, offs, bwH, bwL, tpw,
                                          gn0, gn1, capEff);
    int gBlocks = (gn1 - gn0 + 3) / 4;
    k_gather5<<<gBlocks, 256, 0, stream>>>(iSlot, eaSlot, offs, sup, vup, an,
                                           cw, tpw, d_out, gn0, gn1, capEff,
                                           flag);
  }
}